// Round 2
// baseline (4166.253 us; speedup 1.0000x reference)
//
#include <hip/hip_runtime.h>
#include <hip/hip_fp16.h>
#include <cstdint>
#include <cstddef>

#define L_SEQ 2046      // subsampled sequence length
#define NBATCH 32
#define HID 256
#define M_PAD 65536     // padded row count (l2*32+n), 65472 real rows

typedef _Float16 h2vec __attribute__((ext_vector_type(2)));

static __device__ __forceinline__ uint32_t pack2(float a, float b) {
  __half2 h = __floats2half2_rn(a, b);
  return __builtin_bit_cast(uint32_t, h);
}

static __device__ __forceinline__ float fdot2u(uint32_t w, uint32_t h, float c) {
#if __has_builtin(__builtin_amdgcn_fdot2)
  return __builtin_amdgcn_fdot2(__builtin_bit_cast(h2vec, w),
                                __builtin_bit_cast(h2vec, h), c, false);
#else
  __half2 a = __builtin_bit_cast(__half2, w);
  __half2 b = __builtin_bit_cast(__half2, h);
  float2 fa = __half22float2(a), fb = __half22float2(b);
  return c + fa.x * fb.x + fa.y * fb.y;
#endif
}

// ---- fused conv1 + im2col(for conv2 at even positions), output f16 ----
// A1h[row][j], row = l2*32+n (padded to 65536), j = ci*3+k
//   = y1[n][ci][2*l2+k] = b1[ci] + sum_{c,kk} X[n][c][2*l2+k+kk] * W1[ci][c][kk]
__global__ void k_conv_im2col(const float* __restrict__ X,
                              const float* __restrict__ W1,
                              const float* __restrict__ b1,
                              __half* __restrict__ A1h) {
  int j   = threadIdx.x;     // 0..383
  int row = blockIdx.x;      // 0..65535
  int l2 = row >> 5, n = row & 31;
  float v = 0.f;
  if (l2 < L_SEQ) {
    int ci = j / 3;
    int k  = j - 3 * ci;
    int p  = 2 * l2 + k;                 // <= 4092; reads X up to p+2 <= 4094
    const float* xb = X + (size_t)n * 13 * 4096 + p;
    const float* w  = W1 + ci * 39;
    float acc = b1[ci];
#pragma unroll
    for (int c = 0; c < 13; c++) {
      const float* xp = xb + (size_t)c * 4096;
      acc += xp[0] * w[3*c+0] + xp[1] * w[3*c+1] + xp[2] * w[3*c+2];
    }
    v = acc;
  }
  A1h[(size_t)row * 384 + j] = __float2half(v);
}

// ---- GEMM: C_half[M][ldC] (+col_off) = A_half[M][K] @ B_float[N][K]^T + bias
// grid (M/128, N/128), block 256, 8x8 micro-tile, fp32 accumulate.
// M multiple of 128 (padded), N multiple of 128, K multiple of 32.
__global__ __launch_bounds__(256, 4) void k_gemm_h(
    const __half* __restrict__ A, const float* __restrict__ B,
    const float* __restrict__ bias, __half* __restrict__ C,
    int K, int ldC, int col_off) {
  __shared__ float As[32][132];
  __shared__ float Bs[32][132];
  const int tid = threadIdx.x;
  const int m_blk = blockIdx.x * 128;
  const int n_blk = blockIdx.y * 128;
  const int tx = tid & 15, ty = tid >> 4;
  const int m0 = tx * 8, n0 = ty * 8;
  // B staging: row sr (0..31) + 32*i, k-offset sc (float4)
  const int sr = tid >> 3;
  const int sc = 4 * (tid & 7);
  // A staging: row ar (0..127), 16 halves starting at ak
  const int ar = tid >> 1;
  const int ak = 16 * (tid & 1);

  float acc[8][8];
#pragma unroll
  for (int i = 0; i < 8; i++)
#pragma unroll
    for (int j = 0; j < 8; j++) acc[i][j] = 0.f;

  for (int kc = 0; kc < K; kc += 32) {
    const __half* ap = A + (size_t)(m_blk + ar) * K + kc + ak;
    uint4 h0 = *(const uint4*)(ap);
    uint4 h1 = *(const uint4*)(ap + 8);
    {
      uint32_t hw[8] = {h0.x, h0.y, h0.z, h0.w, h1.x, h1.y, h1.z, h1.w};
#pragma unroll
      for (int p = 0; p < 8; p++) {
        float2 f = __half22float2(__builtin_bit_cast(__half2, hw[p]));
        As[ak + 2*p    ][ar] = f.x;
        As[ak + 2*p + 1][ar] = f.y;
      }
    }
#pragma unroll
    for (int i = 0; i < 4; i++) {
      int r = i * 32 + sr;
      float4 vb = *(const float4*)(B + (size_t)(n_blk + r) * K + kc + sc);
      Bs[sc+0][r] = vb.x; Bs[sc+1][r] = vb.y; Bs[sc+2][r] = vb.z; Bs[sc+3][r] = vb.w;
    }
    __syncthreads();
#pragma unroll 8
    for (int k = 0; k < 32; k++) {
      float a[8], b[8];
      *(float4*)(a)     = *(const float4*)&As[k][m0];
      *(float4*)(a + 4) = *(const float4*)&As[k][m0 + 4];
      *(float4*)(b)     = *(const float4*)&Bs[k][n0];
      *(float4*)(b + 4) = *(const float4*)&Bs[k][n0 + 4];
#pragma unroll
      for (int i = 0; i < 8; i++)
#pragma unroll
        for (int j = 0; j < 8; j++) acc[i][j] += a[i] * b[j];
    }
    __syncthreads();
  }
  float bj[8];
#pragma unroll
  for (int j = 0; j < 8; j++) bj[j] = bias[n_blk + n0 + j];
#pragma unroll
  for (int i = 0; i < 8; i++) {
    uint4 o;
    o.x = pack2(acc[i][0] + bj[0], acc[i][1] + bj[1]);
    o.y = pack2(acc[i][2] + bj[2], acc[i][3] + bj[3]);
    o.z = pack2(acc[i][4] + bj[4], acc[i][5] + bj[5]);
    o.w = pack2(acc[i][6] + bj[6], acc[i][7] + bj[7]);
    *(uint4*)(C + (size_t)(m_blk + m0 + i) * ldC + col_off + n_blk + n0) = o;
  }
}

// ---- GRU recurrence: 64 blocks = (dir,n); 512 thr = (k-half, gate-out g)
// Whh register-resident as packed f16 pairs; h in LDS as f16; hp f32.
__global__ __launch_bounds__(512, 2) void k_gru(
    const __half* __restrict__ gih,
    const float* __restrict__ Whh_f, const float* __restrict__ Whh_b,
    const float* __restrict__ bhh_f, const float* __restrict__ bhh_b,
    float* __restrict__ outF, __half* __restrict__ outBh,
    float* __restrict__ hT) {
  const int blk = blockIdx.x;
  const int dir = blk >> 5;    // 0 fwd, 1 bwd
  const int n   = blk & 31;
  const int tid = threadIdx.x;
  const int g   = tid & 255;
  const int kh  = tid >> 8;    // k-half

  const float* Whh = dir ? Whh_b : Whh_f;
  const float* bhh = dir ? bhh_b : bhh_f;

  uint32_t w0[64], w1[64], w2[64];
  {
    const float* wr0 = Whh + (size_t)g * 256 + 128 * kh;
    const float* wr1 = wr0 + 256 * 256;
    const float* wr2 = wr1 + 256 * 256;
#pragma unroll
    for (int j = 0; j < 64; j++) {
      w0[j] = pack2(wr0[2*j], wr0[2*j+1]);
      w1[j] = pack2(wr1[2*j], wr1[2*j+1]);
      w2[j] = pack2(wr2[2*j], wr2[2*j+1]);
    }
  }
  const float bh0 = bhh[g];
  const float bh1 = bhh[256 + g];
  const float bh2 = bhh[512 + g];

  __shared__ __align__(16) __half hs[256];
  __shared__ float ps[3][256];
  if (tid < 256) hs[tid] = __float2half(0.f);
  float hp = 0.f;
  __syncthreads();

  for (int t = 0; t < L_SEQ; t++) {
    const int l = dir ? (L_SEQ - 1 - t) : t;
    float a0 = 0.f, a1 = 0.f, a2 = 0.f;
#pragma unroll
    for (int q = 0; q < 16; q++) {
      uint4 hq = ((const uint4*)hs)[16 * kh + q];
      a0 = fdot2u(w0[4*q+0], hq.x, a0);
      a0 = fdot2u(w0[4*q+1], hq.y, a0);
      a0 = fdot2u(w0[4*q+2], hq.z, a0);
      a0 = fdot2u(w0[4*q+3], hq.w, a0);
      a1 = fdot2u(w1[4*q+0], hq.x, a1);
      a1 = fdot2u(w1[4*q+1], hq.y, a1);
      a1 = fdot2u(w1[4*q+2], hq.z, a1);
      a1 = fdot2u(w1[4*q+3], hq.w, a1);
      a2 = fdot2u(w2[4*q+0], hq.x, a2);
      a2 = fdot2u(w2[4*q+1], hq.y, a2);
      a2 = fdot2u(w2[4*q+2], hq.z, a2);
      a2 = fdot2u(w2[4*q+3], hq.w, a2);
    }
    if (kh == 1) { ps[0][g] = a0; ps[1][g] = a1; ps[2][g] = a2; }
    __syncthreads();
    if (kh == 0) {
      float hr = a0 + ps[0][g] + bh0;
      float hz = a1 + ps[1][g] + bh1;
      float hn = a2 + ps[2][g] + bh2;
      const __half* gr = gih + ((size_t)l * NBATCH + n) * 1536 + dir * 768 + g;
      float ir  = __half2float(gr[0]);
      float iz  = __half2float(gr[256]);
      float inn = __half2float(gr[512]);
      float rr = 1.f / (1.f + __expf(-(ir + hr)));
      float zz = 1.f / (1.f + __expf(-(iz + hz)));
      float e  = __expf(2.f * (inn + rr * hn));
      float nn = 1.f - 2.f / (e + 1.f);      // tanh, safe at +/-inf
      float hnew = (1.f - zz) * nn + zz * hp;
      hp = hnew;
      size_t oi = ((size_t)l * NBATCH + n) * HID + g;
      if (dir == 0) outF[oi] = hnew;
      else          outBh[oi] = __float2half(hnew);
      hs[g] = __float2half(hnew);
    }
    __syncthreads();
  }
  if (dir == 1 && tid < 256) hT[n * HID + tid] = hp;
}

// ---- combine (in place over outF/d_out): relu(0.5*(out_f + out_b[...,::-1]))
__global__ void k_combine(float* __restrict__ outF,
                          const __half* __restrict__ outBh) {
  int idx = blockIdx.x * 256 + threadIdx.x;   // exactly 2046*32*256 threads
  int c = idx & 255;
  float v = 0.5f * (outF[idx] + __half2float(outBh[idx + 255 - 2 * c]));
  outF[idx] = v > 0.f ? v : 0.f;
}

extern "C" void kernel_launch(void* const* d_in, const int* in_sizes, int n_in,
                              void* d_out, int out_size, void* d_ws, size_t ws_size,
                              hipStream_t stream) {
  const float* X     = (const float*)d_in[0];
  const float* W1    = (const float*)d_in[1];
  const float* b1    = (const float*)d_in[2];
  const float* W2    = (const float*)d_in[3];
  const float* b2    = (const float*)d_in[4];
  const float* Wih_f = (const float*)d_in[5];
  const float* Whh_f = (const float*)d_in[6];
  const float* bih_f = (const float*)d_in[7];
  const float* bhh_f = (const float*)d_in[8];
  const float* Wih_b = (const float*)d_in[9];
  const float* Whh_b = (const float*)d_in[10];
  const float* bih_b = (const float*)d_in[11];
  const float* bhh_b = (const float*)d_in[12];

  // Workspace layout (bytes) — total 251,658,240 B (fits 256 MiB):
  //   gih : [0, 201326592)                 65536 x 1536 halves
  //   A1h : [201326592, 251658240)         65536 x 384 halves (dead after gemm1)
  //   outBh: alias of A1h region           2046*32*256 halves = 33,521,664 B
  char* wsb = (char*)d_ws;
  __half* gih   = (__half*)(wsb);
  __half* A1h   = (__half*)(wsb + 201326592);
  __half* outBh = (__half*)(wsb + 201326592);

  // d_out doubles as scratch: xsubh occupies its first 33.5 MB until the GRU
  // (which overwrites that region with out_f floats).
  float*  outF  = (float*)d_out;
  __half* xsubh = (__half*)d_out;                      // 65536 x 256 halves
  float*  hT    = outF + (size_t)L_SEQ * NBATCH * HID; // tail of d_out

  k_conv_im2col<<<dim3(M_PAD), 384, 0, stream>>>(X, W1, b1, A1h);
  // xsub[65536][256] = A1h[65536][384] @ W2[256][384]^T + b2
  k_gemm_h<<<dim3(512, 2), 256, 0, stream>>>(A1h, W2, b2, xsubh, 384, 256, 0);
  // gi[65536][0:768]    = xsub @ Wih_f^T + bih_f
  k_gemm_h<<<dim3(512, 6), 256, 0, stream>>>(xsubh, Wih_f, bih_f, gih, 256, 1536, 0);
  // gi[65536][768:1536] = xsub @ Wih_b^T + bih_b
  k_gemm_h<<<dim3(512, 6), 256, 0, stream>>>(xsubh, Wih_b, bih_b, gih, 256, 1536, 768);
  k_gru<<<dim3(64), 512, 0, stream>>>(gih, Whh_f, Whh_b, bhh_f, bhh_b, outF, outBh, hT);
  k_combine<<<dim3(65472), 256, 0, stream>>>(outF, outBh);
}